// Round 4
// baseline (967.225 us; speedup 1.0000x reference)
//
#include <hip/hip_runtime.h>

#define NEGV (-1e9f)

__device__ __forceinline__ float ftanh(float x) {
    // tanh(x) = 1 - 2/(exp(2x)+1); exact at +-inf, ~1e-6 rel err
    float e = __expf(2.f * x);
    return 1.f - 2.f * __builtin_amdgcn_rcpf(e + 1.f);
}

// scores[b*S+s] = mask ? v . tanh(feat[b,s,:] @ W + bias) + c : -1e9
// One WG = 64 positions. feat tile (64x256 f32 = 64KB) in LDS. W streamed (L2-resident).
// Wave w -> positions w*16..w*16+15; lane l -> k = 4l..4l+3. 16384 FMA/lane.
template<bool PRETANH>
__global__ __launch_bounds__(256) void score_kernel(
    const float* __restrict__ feat, const int* __restrict__ mask,
    const float* __restrict__ W, const float* __restrict__ bias,
    const float* __restrict__ v, const float* __restrict__ c,
    float* __restrict__ scores, int S)
{
    __shared__ float4 lds4[64 * 64];   // 64 pos x 256 h
    const int t = threadIdx.x;
    const int b = blockIdx.y;
    const int s0 = blockIdx.x * 64;
    const float4* feat4 = (const float4*)feat + ((size_t)b * S + s0) * 64;
    #pragma unroll
    for (int i = 0; i < 16; ++i) {
        int f = t + i * 256;
        float4 val = feat4[f];
        if (PRETANH) { val.x = ftanh(val.x); val.y = ftanh(val.y);
                       val.z = ftanh(val.z); val.w = ftanh(val.w); }
        lds4[f] = val;
    }
    __syncthreads();

    const int wave = t >> 6, lane = t & 63;
    const float4* W4 = (const float4*)W;
    float4 acc[16];
    #pragma unroll
    for (int pp = 0; pp < 16; ++pp) acc[pp] = make_float4(0.f, 0.f, 0.f, 0.f);

    for (int h4 = 0; h4 < 64; ++h4) {
        float4 w0 = W4[(4 * h4 + 0) * 64 + lane];
        float4 w1 = W4[(4 * h4 + 1) * 64 + lane];
        float4 w2 = W4[(4 * h4 + 2) * 64 + lane];
        float4 w3 = W4[(4 * h4 + 3) * 64 + lane];
        #pragma unroll
        for (int pp = 0; pp < 16; ++pp) {
            float4 f = lds4[(wave * 16 + pp) * 64 + h4];  // broadcast, conflict-free
            acc[pp].x += f.x * w0.x + f.y * w1.x + f.z * w2.x + f.w * w3.x;
            acc[pp].y += f.x * w0.y + f.y * w1.y + f.z * w2.y + f.w * w3.y;
            acc[pp].z += f.x * w0.z + f.y * w1.z + f.z * w2.z + f.w * w3.z;
            acc[pp].w += f.x * w0.w + f.y * w1.w + f.z * w2.w + f.w * w3.w;
        }
    }

    float4 bi = ((const float4*)bias)[lane];
    float4 vv = ((const float4*)v)[lane];
    float cc = c[0];
    #pragma unroll
    for (int pp = 0; pp < 16; ++pp) {
        float4 hs = acc[pp];
        float r = ftanh(hs.x + bi.x) * vv.x + ftanh(hs.y + bi.y) * vv.y
                + ftanh(hs.z + bi.z) * vv.z + ftanh(hs.w + bi.w) * vv.w;
        #pragma unroll
        for (int o = 32; o > 0; o >>= 1) r += __shfl_down(r, o);
        if (lane == 0) {
            int pos = s0 + wave * 16 + pp;
            float sc = r + cc;
            scores[(size_t)b * S + pos] = mask[(size_t)b * S + pos] ? sc : NEGV;
        }
    }
}

// out[b, hbase..hbase+63] = sum_s softmax(scores)[s] * feat[b,s,h]
template<bool PRETANH>
__global__ __launch_bounds__(256) void pool_kernel(
    const float* __restrict__ feat, const float* __restrict__ scores,
    float* __restrict__ out, int S)
{
    __shared__ float red[256];
    __shared__ float lds_w[256];
    const int t = threadIdx.x;
    const int b = blockIdx.y;
    const int hbase = blockIdx.x * 64;
    const float* srow = scores + (size_t)b * S;

    float mx = -3e38f;
    for (int s = t; s < S; s += 256) mx = fmaxf(mx, srow[s]);
    red[t] = mx; __syncthreads();
    for (int o = 128; o > 0; o >>= 1) { if (t < o) red[t] = fmaxf(red[t], red[t + o]); __syncthreads(); }
    mx = red[0]; __syncthreads();

    float se = 0.f;
    for (int s = t; s < S; s += 256) se += __expf(srow[s] - mx);
    red[t] = se; __syncthreads();
    for (int o = 128; o > 0; o >>= 1) { if (t < o) red[t] += red[t + o]; __syncthreads(); }
    const float inv = __builtin_amdgcn_rcpf(red[0]);
    __syncthreads();

    const int h = hbase + (t & 63);
    const int sg = t >> 6;
    float acc = 0.f;
    for (int c0 = 0; c0 < S; c0 += 256) {
        lds_w[t] = __expf(srow[c0 + t] - mx) * inv;
        __syncthreads();
        for (int s = sg; s < 256; s += 4) {
            float fv = feat[((size_t)b * S + c0 + s) * 256 + h];
            if (PRETANH) fv = ftanh(fv);
            acc += lds_w[s] * fv;
        }
        __syncthreads();
    }
    red[t] = acc; __syncthreads();
    if (t < 64)
        out[(size_t)b * 256 + hbase + t] = red[t] + red[t + 64] + red[t + 128] + red[t + 192];
}

__global__ __launch_bounds__(256) void code_kernel(
    const float* __restrict__ pool_t, const float* __restrict__ pool_g,
    const float* __restrict__ Wf, const float* __restrict__ bf,
    float* __restrict__ code)
{
    __shared__ float cat[512];
    const int t = threadIdx.x, b = blockIdx.x;
    cat[t]       = ftanh(pool_t[b * 256 + t]);
    cat[t + 256] = ftanh(pool_g[b * 256 + t]);
    __syncthreads();
    float sum = bf[t];
    for (int i = 0; i < 512; ++i) sum += cat[i] * Wf[i * 256 + t];
    code[b * 256 + t] = ftanh(sum);
}

__global__ __launch_bounds__(256) void loss_kernel(
    const float* __restrict__ code, const float* __restrict__ pool_a,
    const float* __restrict__ pool_n, float* __restrict__ out)
{
    __shared__ float wred[4];
    const int t = threadIdx.x, wave = t >> 6, lane = t & 63;
    float wloss = 0.f;
    for (int b = wave; b < 64; b += 4) {
        float4 c4 = ((const float4*)code)[b * 64 + lane];
        float4 a4 = ((const float4*)pool_a)[b * 64 + lane];
        float4 n4 = ((const float4*)pool_n)[b * 64 + lane];
        a4.x = ftanh(ftanh(a4.x)); a4.y = ftanh(ftanh(a4.y));
        a4.z = ftanh(ftanh(a4.z)); a4.w = ftanh(ftanh(a4.w));
        n4.x = ftanh(ftanh(n4.x)); n4.y = ftanh(ftanh(n4.y));
        n4.z = ftanh(ftanh(n4.z)); n4.w = ftanh(ftanh(n4.w));
        float dca = c4.x * a4.x + c4.y * a4.y + c4.z * a4.z + c4.w * a4.w;
        float dcn = c4.x * n4.x + c4.y * n4.y + c4.z * n4.z + c4.w * n4.w;
        float dcc = c4.x * c4.x + c4.y * c4.y + c4.z * c4.z + c4.w * c4.w;
        float daa = a4.x * a4.x + a4.y * a4.y + a4.z * a4.z + a4.w * a4.w;
        float dnn = n4.x * n4.x + n4.y * n4.y + n4.z * n4.z + n4.w * n4.w;
        #pragma unroll
        for (int o = 32; o > 0; o >>= 1) {
            dca += __shfl_down(dca, o);
            dcn += __shfl_down(dcn, o);
            dcc += __shfl_down(dcc, o);
            daa += __shfl_down(daa, o);
            dnn += __shfl_down(dnn, o);
        }
        if (lane == 0) {
            float ca = dca / fmaxf(sqrtf(dcc) * sqrtf(daa), 1e-8f);
            float cn = dcn / fmaxf(sqrtf(dcc) * sqrtf(dnn), 1e-8f);
            wloss += fmaxf(0.6f - ca + cn, 0.f);
        }
    }
    if (lane == 0) wred[wave] = wloss;
    __syncthreads();
    if (t == 0) out[0] = (wred[0] + wred[1] + wred[2] + wred[3]) * (1.f / 64.f);
}

extern "C" void kernel_launch(void* const* d_in, const int* in_sizes, int n_in,
                              void* d_out, int out_size, void* d_ws, size_t ws_size,
                              hipStream_t stream) {
    const float* token_feat = (const float*)d_in[0];
    const int*   token_mask = (const int*)d_in[1];
    const float* graph_feat = (const float*)d_in[2];
    const int*   graph_mask = (const int*)d_in[3];
    const float* da_feat    = (const float*)d_in[4];
    const int*   da_mask    = (const int*)d_in[5];
    const float* dn_feat    = (const float*)d_in[6];
    const int*   dn_mask    = (const int*)d_in[7];
    const float* Wt = (const float*)d_in[8];
    const float* bt = (const float*)d_in[9];
    const float* vt = (const float*)d_in[10];
    const float* ct = (const float*)d_in[11];
    const float* Wg = (const float*)d_in[12];
    const float* bg = (const float*)d_in[13];
    const float* vg = (const float*)d_in[14];
    const float* cg = (const float*)d_in[15];
    const float* Wd = (const float*)d_in[16];
    const float* bd = (const float*)d_in[17];
    const float* vd = (const float*)d_in[18];
    const float* cd = (const float*)d_in[19];
    const float* Wf = (const float*)d_in[20];
    const float* bf = (const float*)d_in[21];

    float* ws   = (float*)d_ws;
    float* sc_t = ws;                    // 64*2048
    float* sc_g = sc_t + 64 * 2048;      // 64*512
    float* sc_a = sc_g + 64 * 512;
    float* sc_n = sc_a + 64 * 512;
    float* po_t = sc_n + 64 * 512;       // 64*256 each
    float* po_g = po_t + 64 * 256;
    float* po_a = po_g + 64 * 256;
    float* po_n = po_a + 64 * 256;
    float* code = po_n + 64 * 256;

    score_kernel<false><<<dim3(32, 64), 256, 0, stream>>>(token_feat, token_mask, Wt, bt, vt, ct, sc_t, 2048);
    score_kernel<true ><<<dim3(8, 64),  256, 0, stream>>>(graph_feat, graph_mask, Wg, bg, vg, cg, sc_g, 512);
    score_kernel<false><<<dim3(8, 64),  256, 0, stream>>>(da_feat, da_mask, Wd, bd, vd, cd, sc_a, 512);
    score_kernel<false><<<dim3(8, 64),  256, 0, stream>>>(dn_feat, dn_mask, Wd, bd, vd, cd, sc_n, 512);

    pool_kernel<false><<<dim3(4, 64), 256, 0, stream>>>(token_feat, sc_t, po_t, 2048);
    pool_kernel<true ><<<dim3(4, 64), 256, 0, stream>>>(graph_feat, sc_g, po_g, 512);
    pool_kernel<false><<<dim3(4, 64), 256, 0, stream>>>(da_feat, sc_a, po_a, 512);
    pool_kernel<false><<<dim3(4, 64), 256, 0, stream>>>(dn_feat, sc_n, po_n, 512);

    code_kernel<<<64, 256, 0, stream>>>(po_t, po_g, Wf, bf, code);
    loss_kernel<<<1, 256, 0, stream>>>(code, po_a, po_n, (float*)d_out);
}

// Round 7
// 496.157 us; speedup vs baseline: 1.9494x; 1.9494x over previous
//
#include <hip/hip_runtime.h>

#define NEGV (-1e9f)

typedef short s16x8 __attribute__((ext_vector_type(8)));
typedef float f32x4 __attribute__((ext_vector_type(4)));

__device__ __forceinline__ float ftanh(float x) {
    // tanh(x) = 1 - 2/(exp(2x)+1); exact at +-inf, ~1e-6 rel err
    float e = __expf(2.f * x);
    return 1.f - 2.f * __builtin_amdgcn_rcpf(e + 1.f);
}

__device__ __forceinline__ unsigned short f2bf(float f) {
    // RNE f32 -> bf16 (inputs are finite, no NaN handling needed)
    unsigned u = __float_as_uint(f);
    u = u + 0x7FFFu + ((u >> 16) & 1u);
    return (unsigned short)(u >> 16);
}

// Convert W (256x256 f32, row = k, col = out) into B-fragment-ordered bf16:
// slot = ((nblk*8 + kk)*64 + lane), 8 bf16 per slot:
//   elem j = W[kk*32 + (lane>>4)*8 + j][nblk*16 + (lane&15)]
// so the score kernel's B-frag load is one coalesced 16B load per lane.
__global__ __launch_bounds__(256) void wprep_kernel(
    const float* __restrict__ W0, const float* __restrict__ W1, const float* __restrict__ W2,
    unsigned short* __restrict__ O0, unsigned short* __restrict__ O1, unsigned short* __restrict__ O2)
{
    const float* W = blockIdx.y == 0 ? W0 : (blockIdx.y == 1 ? W1 : W2);
    unsigned short* O = blockIdx.y == 0 ? O0 : (blockIdx.y == 1 ? O1 : O2);
    int slot = blockIdx.x * 256 + threadIdx.x;   // 0..8191
    int lane = slot & 63;
    int kk   = (slot >> 6) & 7;
    int nblk = slot >> 9;
    int col  = nblk * 16 + (lane & 15);
    int k0   = kk * 32 + (lane >> 4) * 8;
    s16x8 v;
    #pragma unroll
    for (int j = 0; j < 8; ++j) v[j] = (short)f2bf(W[(k0 + j) * 256 + col]);
    ((s16x8*)O)[slot] = v;
}

// scores[b*S+s] = mask ? v . tanh(feat[b,s,:] @ W + bias) + c : -1e9
// MFMA version: WG = 256 thr = 4 waves; 64 positions per WG.
// feat tile -> bf16 LDS (XOR-swizzled, G4: row-major [64][512B] would be a
// 16-way bank conflict on ds_read_b128; addr ^= (row&7)<<4 spreads it).
// Wave w owns output cols w*64..w*64+63: 4x4 acc blocks of 16x16, K=256.
// B-frags stream from the prepacked Wb (L2-resident, coalesced).
template<bool PRETANH>
__global__ __launch_bounds__(256) void score_mfma_kernel(
    const float* __restrict__ feat, const int* __restrict__ mask,
    const unsigned short* __restrict__ Wb, const float* __restrict__ bias,
    const float* __restrict__ v, const float* __restrict__ c,
    float* __restrict__ scores, int S)
{
    __shared__ char  ldsA[64 * 512];   // 64 pos x 256 bf16, swizzled
    __shared__ float red[64 * 4];
    const int t = threadIdx.x;
    const int b = blockIdx.y;
    const int s0 = blockIdx.x * 64;

    // ---- stage: 64 rows x 256 cols f32 -> bf16 LDS ----
    const float4* feat4 = (const float4*)(feat + ((size_t)b * S + s0) * 256);
    #pragma unroll
    for (int i = 0; i < 8; ++i) {
        int chunk = t + i * 256;           // 0..2047, 16B bf16 chunks
        int row = chunk >> 5;              // 32 chunks per row
        int col16 = chunk & 31;
        float4 f0 = feat4[row * 64 + col16 * 2];
        float4 f1 = feat4[row * 64 + col16 * 2 + 1];
        if (PRETANH) {
            f0.x = ftanh(f0.x); f0.y = ftanh(f0.y); f0.z = ftanh(f0.z); f0.w = ftanh(f0.w);
            f1.x = ftanh(f1.x); f1.y = ftanh(f1.y); f1.z = ftanh(f1.z); f1.w = ftanh(f1.w);
        }
        s16x8 pk;
        pk[0] = (short)f2bf(f0.x); pk[1] = (short)f2bf(f0.y);
        pk[2] = (short)f2bf(f0.z); pk[3] = (short)f2bf(f0.w);
        pk[4] = (short)f2bf(f1.x); pk[5] = (short)f2bf(f1.y);
        pk[6] = (short)f2bf(f1.z); pk[7] = (short)f2bf(f1.w);
        int addr = (row * 512 + col16 * 16) ^ ((row & 7) << 4);
        *(s16x8*)(ldsA + addr) = pk;
    }
    __syncthreads();

    // ---- MFMA: A = feat rows (M=64), B = W cols (N=64 per wave), K=256 ----
    const int w = t >> 6, lane = t & 63;
    const int g = lane >> 4, li = lane & 15;
    f32x4 acc[4][4];
    #pragma unroll
    for (int m = 0; m < 4; ++m)
        #pragma unroll
        for (int n = 0; n < 4; ++n)
            acc[m][n] = (f32x4)0.f;

    const s16x8* WB = (const s16x8*)Wb;
    #pragma unroll
    for (int kk = 0; kk < 8; ++kk) {
        s16x8 a[4];
        #pragma unroll
        for (int m = 0; m < 4; ++m) {
            int row = m * 16 + li;         // A row = lane&15 within 16-block
            int addr = (row * 512 + kk * 64 + g * 16) ^ ((row & 7) << 4);
            a[m] = *(const s16x8*)(ldsA + addr);
        }
        #pragma unroll
        for (int n = 0; n < 4; ++n) {
            s16x8 bfr = WB[((w * 4 + n) * 8 + kk) * 64 + lane];
            #pragma unroll
            for (int m = 0; m < 4; ++m)
                acc[m][n] = __builtin_amdgcn_mfma_f32_16x16x32_bf16(a[m], bfr, acc[m][n], 0, 0, 0);
        }
    }

    // ---- epilogue: score partial = sum_cols tanh(x + bias)*v ----
    // D layout (m89): col = lane&15 (within n-block), row = (lane>>4)*4 + reg.
    float bi[4], vv[4];
    #pragma unroll
    for (int n = 0; n < 4; ++n) {
        int col = w * 64 + n * 16 + li;
        bi[n] = bias[col]; vv[n] = v[col];
    }
    #pragma unroll
    for (int m = 0; m < 4; ++m) {
        #pragma unroll
        for (int reg = 0; reg < 4; ++reg) {
            float val = 0.f;
            #pragma unroll
            for (int n = 0; n < 4; ++n)
                val += ftanh(acc[m][n][reg] + bi[n]) * vv[n];
            val += __shfl_xor(val, 1);
            val += __shfl_xor(val, 2);
            val += __shfl_xor(val, 4);
            val += __shfl_xor(val, 8);
            if (li == 0) red[(m * 16 + g * 4 + reg) * 4 + w] = val;
        }
    }
    __syncthreads();
    if (t < 64) {
        float sc = red[t * 4] + red[t * 4 + 1] + red[t * 4 + 2] + red[t * 4 + 3] + c[0];
        size_t idx = (size_t)b * S + s0 + t;
        scores[idx] = mask[idx] ? sc : NEGV;
    }
}

// out[b, hbase..hbase+63] = sum_s softmax(scores)[s] * feat[b,s,h]
// Single-pass weights in LDS (unnormalized; normalize once at the end),
// 4 independent accumulators to break the fmac dependence chain.
template<bool PRETANH>
__global__ __launch_bounds__(256) void pool_kernel(
    const float* __restrict__ feat, const float* __restrict__ scores,
    float* __restrict__ out, int S)
{
    __shared__ float wts[2048];
    __shared__ float red[256];
    const int t = threadIdx.x;
    const int b = blockIdx.y;
    const int hbase = blockIdx.x * 64;
    const float* srow = scores + (size_t)b * S;

    float mx = -3e38f;
    for (int s = t; s < S; s += 256) mx = fmaxf(mx, srow[s]);
    red[t] = mx; __syncthreads();
    for (int o = 128; o > 0; o >>= 1) { if (t < o) red[t] = fmaxf(red[t], red[t + o]); __syncthreads(); }
    mx = red[0]; __syncthreads();

    float se = 0.f;
    for (int s = t; s < S; s += 256) { float e = __expf(srow[s] - mx); wts[s] = e; se += e; }
    red[t] = se; __syncthreads();
    for (int o = 128; o > 0; o >>= 1) { if (t < o) red[t] += red[t + o]; __syncthreads(); }
    const float inv = __builtin_amdgcn_rcpf(red[0]);
    __syncthreads();

    const int h = hbase + (t & 63);
    const int sg = t >> 6;
    const float* fcol = feat + (size_t)b * S * 256 + h;
    float a0 = 0.f, a1 = 0.f, a2 = 0.f, a3 = 0.f;
    for (int s = sg; s < S; s += 16) {
        float f0 = fcol[(size_t)(s     ) * 256];
        float f1 = fcol[(size_t)(s +  4) * 256];
        float f2 = fcol[(size_t)(s +  8) * 256];
        float f3 = fcol[(size_t)(s + 12) * 256];
        if (PRETANH) { f0 = ftanh(f0); f1 = ftanh(f1); f2 = ftanh(f2); f3 = ftanh(f3); }
        a0 += wts[s] * f0; a1 += wts[s + 4] * f1;
        a2 += wts[s + 8] * f2; a3 += wts[s + 12] * f3;
    }
    red[t] = (a0 + a1) + (a2 + a3); __syncthreads();
    if (t < 64)
        out[(size_t)b * 256 + hbase + t] =
            (red[t] + red[t + 64] + red[t + 128] + red[t + 192]) * inv;
}

__global__ __launch_bounds__(256) void code_kernel(
    const float* __restrict__ pool_t, const float* __restrict__ pool_g,
    const float* __restrict__ Wf, const float* __restrict__ bf,
    float* __restrict__ code)
{
    __shared__ float cat[512];
    const int t = threadIdx.x, b = blockIdx.x;
    cat[t]       = ftanh(pool_t[b * 256 + t]);
    cat[t + 256] = ftanh(pool_g[b * 256 + t]);
    __syncthreads();
    float sum = bf[t];
    for (int i = 0; i < 512; ++i) sum += cat[i] * Wf[i * 256 + t];
    code[b * 256 + t] = ftanh(sum);
}

__global__ __launch_bounds__(256) void loss_kernel(
    const float* __restrict__ code, const float* __restrict__ pool_a,
    const float* __restrict__ pool_n, float* __restrict__ out)
{
    __shared__ float wred[4];
    const int t = threadIdx.x, wave = t >> 6, lane = t & 63;
    float wloss = 0.f;
    for (int b = wave; b < 64; b += 4) {
        float4 c4 = ((const float4*)code)[b * 64 + lane];
        float4 a4 = ((const float4*)pool_a)[b * 64 + lane];
        float4 n4 = ((const float4*)pool_n)[b * 64 + lane];
        a4.x = ftanh(ftanh(a4.x)); a4.y = ftanh(ftanh(a4.y));
        a4.z = ftanh(ftanh(a4.z)); a4.w = ftanh(ftanh(a4.w));
        n4.x = ftanh(ftanh(n4.x)); n4.y = ftanh(ftanh(n4.y));
        n4.z = ftanh(ftanh(n4.z)); n4.w = ftanh(ftanh(n4.w));
        float dca = c4.x * a4.x + c4.y * a4.y + c4.z * a4.z + c4.w * a4.w;
        float dcn = c4.x * n4.x + c4.y * n4.y + c4.z * n4.z + c4.w * n4.w;
        float dcc = c4.x * c4.x + c4.y * c4.y + c4.z * c4.z + c4.w * c4.w;
        float daa = a4.x * a4.x + a4.y * a4.y + a4.z * a4.z + a4.w * a4.w;
        float dnn = n4.x * n4.x + n4.y * n4.y + n4.z * n4.z + n4.w * n4.w;
        #pragma unroll
        for (int o = 32; o > 0; o >>= 1) {
            dca += __shfl_down(dca, o);
            dcn += __shfl_down(dcn, o);
            dcc += __shfl_down(dcc, o);
            daa += __shfl_down(daa, o);
            dnn += __shfl_down(dnn, o);
        }
        if (lane == 0) {
            float ca = dca / fmaxf(sqrtf(dcc) * sqrtf(daa), 1e-8f);
            float cn = dcn / fmaxf(sqrtf(dcc) * sqrtf(dnn), 1e-8f);
            wloss += fmaxf(0.6f - ca + cn, 0.f);
        }
    }
    if (lane == 0) wred[wave] = wloss;
    __syncthreads();
    if (t == 0) out[0] = (wred[0] + wred[1] + wred[2] + wred[3]) * (1.f / 64.f);
}

extern "C" void kernel_launch(void* const* d_in, const int* in_sizes, int n_in,
                              void* d_out, int out_size, void* d_ws, size_t ws_size,
                              hipStream_t stream) {
    const float* token_feat = (const float*)d_in[0];
    const int*   token_mask = (const int*)d_in[1];
    const float* graph_feat = (const float*)d_in[2];
    const int*   graph_mask = (const int*)d_in[3];
    const float* da_feat    = (const float*)d_in[4];
    const int*   da_mask    = (const int*)d_in[5];
    const float* dn_feat    = (const float*)d_in[6];
    const int*   dn_mask    = (const int*)d_in[7];
    const float* Wt = (const float*)d_in[8];
    const float* bt = (const float*)d_in[9];
    const float* vt = (const float*)d_in[10];
    const float* ct = (const float*)d_in[11];
    const float* Wg = (const float*)d_in[12];
    const float* bg = (const float*)d_in[13];
    const float* vg = (const float*)d_in[14];
    const float* cg = (const float*)d_in[15];
    const float* Wd = (const float*)d_in[16];
    const float* bd = (const float*)d_in[17];
    const float* vd = (const float*)d_in[18];
    const float* cd = (const float*)d_in[19];
    const float* Wf = (const float*)d_in[20];
    const float* bf = (const float*)d_in[21];

    float* ws   = (float*)d_ws;
    float* sc_t = ws;                    // 64*2048
    float* sc_g = sc_t + 64 * 2048;      // 64*512
    float* sc_a = sc_g + 64 * 512;
    float* sc_n = sc_a + 64 * 512;
    float* po_t = sc_n + 64 * 512;       // 64*256 each
    float* po_g = po_t + 64 * 256;
    float* po_a = po_g + 64 * 256;
    float* po_n = po_a + 64 * 256;
    float* code = po_n + 64 * 256;
    unsigned short* wb_t = (unsigned short*)(code + 64 * 256);  // 65536 bf16 each
    unsigned short* wb_g = wb_t + 65536;
    unsigned short* wb_d = wb_g + 65536;

    wprep_kernel<<<dim3(32, 3), 256, 0, stream>>>(Wt, Wg, Wd, wb_t, wb_g, wb_d);

    score_mfma_kernel<false><<<dim3(32, 64), 256, 0, stream>>>(token_feat, token_mask, wb_t, bt, vt, ct, sc_t, 2048);
    score_mfma_kernel<true ><<<dim3(8, 64),  256, 0, stream>>>(graph_feat, graph_mask, wb_g, bg, vg, cg, sc_g, 512);
    score_mfma_kernel<false><<<dim3(8, 64),  256, 0, stream>>>(da_feat, da_mask, wb_d, bd, vd, cd, sc_a, 512);
    score_mfma_kernel<false><<<dim3(8, 64),  256, 0, stream>>>(dn_feat, dn_mask, wb_d, bd, vd, cd, sc_n, 512);

    pool_kernel<false><<<dim3(4, 64), 256, 0, stream>>>(token_feat, sc_t, po_t, 2048);
    pool_kernel<true ><<<dim3(4, 64), 256, 0, stream>>>(graph_feat, sc_g, po_g, 512);
    pool_kernel<false><<<dim3(4, 64), 256, 0, stream>>>(da_feat, sc_a, po_a, 512);
    pool_kernel<false><<<dim3(4, 64), 256, 0, stream>>>(dn_feat, sc_n, po_n, 512);

    code_kernel<<<64, 256, 0, stream>>>(po_t, po_g, Wf, bf, code);
    loss_kernel<<<1, 256, 0, stream>>>(code, po_a, po_n, (float*)d_out);
}

// Round 8
// 437.340 us; speedup vs baseline: 2.2116x; 1.1345x over previous
//
#include <hip/hip_runtime.h>

#define NEGV (-1e9f)

typedef short s16x8 __attribute__((ext_vector_type(8)));
typedef float f32x4 __attribute__((ext_vector_type(4)));

__device__ __forceinline__ float ftanh(float x) {
    float e = __expf(2.f * x);
    return 1.f - 2.f * __builtin_amdgcn_rcpf(e + 1.f);
}

__device__ __forceinline__ unsigned short f2bf(float f) {
    unsigned u = __float_as_uint(f);
    u = u + 0x7FFFu + ((u >> 16) & 1u);
    return (unsigned short)(u >> 16);
}

__device__ __forceinline__ float bf2f(unsigned short u) {
    return __uint_as_float(((unsigned)u) << 16);
}

// W (256x256 f32, row=k, col=out) -> B-fragment-ordered bf16 (one coalesced
// 16B load per lane per fragment in the score kernel).
__global__ __launch_bounds__(256) void wprep_kernel(
    const float* __restrict__ W0, const float* __restrict__ W1, const float* __restrict__ W2,
    unsigned short* __restrict__ O0, unsigned short* __restrict__ O1, unsigned short* __restrict__ O2)
{
    const float* W = blockIdx.y == 0 ? W0 : (blockIdx.y == 1 ? W1 : W2);
    unsigned short* O = blockIdx.y == 0 ? O0 : (blockIdx.y == 1 ? O1 : O2);
    int slot = blockIdx.x * 256 + threadIdx.x;   // 0..8191
    int lane = slot & 63;
    int kk   = (slot >> 6) & 7;
    int nblk = slot >> 9;
    int col  = nblk * 16 + (lane & 15);
    int k0   = kk * 32 + (lane >> 4) * 8;
    s16x8 v;
    #pragma unroll
    for (int j = 0; j < 8; ++j) v[j] = (short)f2bf(W[(k0 + j) * 256 + col]);
    ((s16x8*)O)[slot] = v;
}

// Fused: scores (MFMA) + tile-softmax partial pooling.
// partial layout per (b, tile): [256 weighted-sum floats][m][l][pad x2] = 260.
template<bool PRETANH>
__global__ __launch_bounds__(256) void score_pool_kernel(
    const float* __restrict__ feat, const int* __restrict__ mask,
    const unsigned short* __restrict__ Wb, const float* __restrict__ bias,
    const float* __restrict__ v, const float* __restrict__ c,
    float* __restrict__ partial, int S)
{
    __shared__ char  ldsA[64 * 512];   // 64 pos x 256 bf16, XOR-swizzled
    __shared__ float red[64 * 4];
    __shared__ float s_lds[64];
    __shared__ float msk_lds[64];
    __shared__ float p_lds[64];
    __shared__ float pbuf[4 * 256];
    const int t = threadIdx.x;
    const int b = blockIdx.y;
    const int s0 = blockIdx.x * 64;

    // ---- stage: two-phase (16 loads in flight per thread) f32 -> bf16 LDS ----
    const float4* feat4 = (const float4*)(feat + ((size_t)b * S + s0) * 256);
    float4 r[16];
    #pragma unroll
    for (int i = 0; i < 8; ++i) {
        int chunk = t + i * 256;
        int row = chunk >> 5;
        int col16 = chunk & 31;
        r[2 * i]     = feat4[row * 64 + col16 * 2];
        r[2 * i + 1] = feat4[row * 64 + col16 * 2 + 1];
    }
    #pragma unroll
    for (int i = 0; i < 8; ++i) {
        int chunk = t + i * 256;
        int row = chunk >> 5;
        int col16 = chunk & 31;
        float4 f0 = r[2 * i], f1 = r[2 * i + 1];
        if (PRETANH) {
            f0.x = ftanh(f0.x); f0.y = ftanh(f0.y); f0.z = ftanh(f0.z); f0.w = ftanh(f0.w);
            f1.x = ftanh(f1.x); f1.y = ftanh(f1.y); f1.z = ftanh(f1.z); f1.w = ftanh(f1.w);
        }
        s16x8 pk;
        pk[0] = (short)f2bf(f0.x); pk[1] = (short)f2bf(f0.y);
        pk[2] = (short)f2bf(f0.z); pk[3] = (short)f2bf(f0.w);
        pk[4] = (short)f2bf(f1.x); pk[5] = (short)f2bf(f1.y);
        pk[6] = (short)f2bf(f1.z); pk[7] = (short)f2bf(f1.w);
        int addr = (row * 512 + col16 * 16) ^ ((row & 7) << 4);
        *(s16x8*)(ldsA + addr) = pk;
    }
    __syncthreads();

    // ---- MFMA: A = feat rows (M=64), B = W cols (N=64 per wave), K=256 ----
    const int w = t >> 6, lane = t & 63;
    const int g = lane >> 4, li = lane & 15;
    f32x4 acc[4][4];
    #pragma unroll
    for (int m = 0; m < 4; ++m)
        #pragma unroll
        for (int n = 0; n < 4; ++n)
            acc[m][n] = (f32x4)0.f;

    const s16x8* WB = (const s16x8*)Wb;
    #pragma unroll
    for (int kk = 0; kk < 8; ++kk) {
        s16x8 a[4];
        #pragma unroll
        for (int m = 0; m < 4; ++m) {
            int row = m * 16 + li;
            int addr = (row * 512 + kk * 64 + g * 16) ^ ((row & 7) << 4);
            a[m] = *(const s16x8*)(ldsA + addr);
        }
        #pragma unroll
        for (int n = 0; n < 4; ++n) {
            s16x8 bfr = WB[((w * 4 + n) * 8 + kk) * 64 + lane];
            #pragma unroll
            for (int m = 0; m < 4; ++m)
                acc[m][n] = __builtin_amdgcn_mfma_f32_16x16x32_bf16(a[m], bfr, acc[m][n], 0, 0, 0);
        }
    }

    // ---- scores: sum_cols tanh(x + bias)*v.  D layout (m89): col=lane&15,
    // row=(lane>>4)*4+reg. ----
    float bi[4], vv[4];
    #pragma unroll
    for (int n = 0; n < 4; ++n) {
        int col = w * 64 + n * 16 + li;
        bi[n] = bias[col]; vv[n] = v[col];
    }
    #pragma unroll
    for (int m = 0; m < 4; ++m) {
        #pragma unroll
        for (int reg = 0; reg < 4; ++reg) {
            float val = 0.f;
            #pragma unroll
            for (int n = 0; n < 4; ++n)
                val += ftanh(acc[m][n][reg] + bi[n]) * vv[n];
            val += __shfl_xor(val, 1);
            val += __shfl_xor(val, 2);
            val += __shfl_xor(val, 4);
            val += __shfl_xor(val, 8);
            if (li == 0) red[(m * 16 + g * 4 + reg) * 4 + w] = val;
        }
    }
    __syncthreads();
    if (t < 64) {
        float sc = red[t * 4] + red[t * 4 + 1] + red[t * 4 + 2] + red[t * 4 + 3] + c[0];
        size_t idx = (size_t)b * S + s0 + t;
        int mk = mask[idx];
        s_lds[t]   = mk ? sc : NEGV;
        msk_lds[t] = mk ? 1.f : 0.f;
    }
    __syncthreads();

    // ---- tile softmax: m, p, l (all waves compute identically) ----
    float sl = s_lds[lane], ml = msk_lds[lane];
    float mt = sl;
    #pragma unroll
    for (int o = 1; o < 64; o <<= 1) mt = fmaxf(mt, __shfl_xor(mt, o));
    float p = __expf(sl - mt) * ml;   // all-masked tile: exp(0)*0 = 0
    float lsum = p;
    #pragma unroll
    for (int o = 1; o < 64; o <<= 1) lsum += __shfl_xor(lsum, o);
    if (w == 0) p_lds[lane] = p;
    __syncthreads();

    // ---- weighted sum: wave w covers s in [w*16, w*16+16), lane covers
    // h = hb*128 + lane*2 (+1).  4B LDS reads, conflict-free. ----
    float2 wacc[2];
    wacc[0] = make_float2(0.f, 0.f); wacc[1] = make_float2(0.f, 0.f);
    #pragma unroll
    for (int hb = 0; hb < 2; ++hb) {
        #pragma unroll
        for (int j = 0; j < 16; ++j) {
            int s = w * 16 + j;
            float ps = p_lds[s];
            int byte = (s * 512 + hb * 256 + lane * 4) ^ ((s & 7) << 4);
            unsigned pair = *(const unsigned*)(ldsA + byte);
            wacc[hb].x += ps * bf2f((unsigned short)(pair & 0xffffu));
            wacc[hb].y += ps * bf2f((unsigned short)(pair >> 16));
        }
    }
    #pragma unroll
    for (int hb = 0; hb < 2; ++hb)
        *(float2*)&pbuf[w * 256 + hb * 128 + lane * 2] = wacc[hb];
    __syncthreads();

    float* gp = partial + ((size_t)b * (S >> 6) + blockIdx.x) * 260;
    gp[t >= 256 ? 0 : t] = pbuf[t] + pbuf[256 + t] + pbuf[512 + t] + pbuf[768 + t]; // t<256 always
    if (t == 0) { gp[256] = mt; gp[257] = lsum; }
}

// Merge tile partials with max-rescaling: out[b,h] = sum_t p_t[h] e^{m_t-mg} / sum_t l_t e^{m_t-mg}
__global__ __launch_bounds__(256) void combine_kernel(
    const float* __restrict__ pt_t, const float* __restrict__ pt_g,
    const float* __restrict__ pt_a, const float* __restrict__ pt_n,
    float* __restrict__ po_t, float* __restrict__ po_g,
    float* __restrict__ po_a, float* __restrict__ po_n)
{
    const int pool = blockIdx.y, b = blockIdx.x, t = threadIdx.x;
    const float* pb; float* out; int T;
    if      (pool == 0) { pb = pt_t; out = po_t; T = 32; }
    else if (pool == 1) { pb = pt_g; out = po_g; T = 8;  }
    else if (pool == 2) { pb = pt_a; out = po_a; T = 8;  }
    else                { pb = pt_n; out = po_n; T = 8;  }
    pb += (size_t)b * T * 260;

    float mg = -3e38f;
    for (int k = 0; k < T; ++k) mg = fmaxf(mg, pb[k * 260 + 256]);
    float lg = 0.f, acc = 0.f;
    for (int k = 0; k < T; ++k) {
        float sc = __expf(pb[k * 260 + 256] - mg);
        lg  += pb[k * 260 + 257] * sc;
        acc += pb[k * 260 + t] * sc;
    }
    out[b * 256 + t] = acc / lg;
}

__global__ __launch_bounds__(256) void code_kernel(
    const float* __restrict__ pool_t, const float* __restrict__ pool_g,
    const float* __restrict__ Wf, const float* __restrict__ bf,
    float* __restrict__ code)
{
    __shared__ float cat[512];
    const int t = threadIdx.x, b = blockIdx.x;
    cat[t]       = ftanh(pool_t[b * 256 + t]);
    cat[t + 256] = ftanh(pool_g[b * 256 + t]);
    __syncthreads();
    float sum = bf[t];
    for (int i = 0; i < 512; ++i) sum += cat[i] * Wf[i * 256 + t];
    code[b * 256 + t] = ftanh(sum);
}

__global__ __launch_bounds__(256) void loss_kernel(
    const float* __restrict__ code, const float* __restrict__ pool_a,
    const float* __restrict__ pool_n, float* __restrict__ out)
{
    __shared__ float wred[4];
    const int t = threadIdx.x, wave = t >> 6, lane = t & 63;
    float wloss = 0.f;
    for (int b = wave; b < 64; b += 4) {
        float4 c4 = ((const float4*)code)[b * 64 + lane];
        float4 a4 = ((const float4*)pool_a)[b * 64 + lane];
        float4 n4 = ((const float4*)pool_n)[b * 64 + lane];
        a4.x = ftanh(ftanh(a4.x)); a4.y = ftanh(ftanh(a4.y));
        a4.z = ftanh(ftanh(a4.z)); a4.w = ftanh(ftanh(a4.w));
        n4.x = ftanh(ftanh(n4.x)); n4.y = ftanh(ftanh(n4.y));
        n4.z = ftanh(ftanh(n4.z)); n4.w = ftanh(ftanh(n4.w));
        float dca = c4.x * a4.x + c4.y * a4.y + c4.z * a4.z + c4.w * a4.w;
        float dcn = c4.x * n4.x + c4.y * n4.y + c4.z * n4.z + c4.w * n4.w;
        float dcc = c4.x * c4.x + c4.y * c4.y + c4.z * c4.z + c4.w * c4.w;
        float daa = a4.x * a4.x + a4.y * a4.y + a4.z * a4.z + a4.w * a4.w;
        float dnn = n4.x * n4.x + n4.y * n4.y + n4.z * n4.z + n4.w * n4.w;
        #pragma unroll
        for (int o = 32; o > 0; o >>= 1) {
            dca += __shfl_down(dca, o);
            dcn += __shfl_down(dcn, o);
            dcc += __shfl_down(dcc, o);
            daa += __shfl_down(daa, o);
            dnn += __shfl_down(dnn, o);
        }
        if (lane == 0) {
            float ca = dca / fmaxf(sqrtf(dcc) * sqrtf(daa), 1e-8f);
            float cn = dcn / fmaxf(sqrtf(dcc) * sqrtf(dnn), 1e-8f);
            wloss += fmaxf(0.6f - ca + cn, 0.f);
        }
    }
    if (lane == 0) wred[wave] = wloss;
    __syncthreads();
    if (t == 0) out[0] = (wred[0] + wred[1] + wred[2] + wred[3]) * (1.f / 64.f);
}

extern "C" void kernel_launch(void* const* d_in, const int* in_sizes, int n_in,
                              void* d_out, int out_size, void* d_ws, size_t ws_size,
                              hipStream_t stream) {
    const float* token_feat = (const float*)d_in[0];
    const int*   token_mask = (const int*)d_in[1];
    const float* graph_feat = (const float*)d_in[2];
    const int*   graph_mask = (const int*)d_in[3];
    const float* da_feat    = (const float*)d_in[4];
    const int*   da_mask    = (const int*)d_in[5];
    const float* dn_feat    = (const float*)d_in[6];
    const int*   dn_mask    = (const int*)d_in[7];
    const float* Wt = (const float*)d_in[8];
    const float* bt = (const float*)d_in[9];
    const float* vt = (const float*)d_in[10];
    const float* ct = (const float*)d_in[11];
    const float* Wg = (const float*)d_in[12];
    const float* bg = (const float*)d_in[13];
    const float* vg = (const float*)d_in[14];
    const float* cg = (const float*)d_in[15];
    const float* Wd = (const float*)d_in[16];
    const float* bd = (const float*)d_in[17];
    const float* vd = (const float*)d_in[18];
    const float* cd = (const float*)d_in[19];
    const float* Wf = (const float*)d_in[20];
    const float* bf = (const float*)d_in[21];

    float* ws   = (float*)d_ws;
    float* pt_t = ws;                        // 64*32*260
    float* pt_g = pt_t + 64 * 32 * 260;      // 64*8*260 each
    float* pt_a = pt_g + 64 * 8 * 260;
    float* pt_n = pt_a + 64 * 8 * 260;
    float* po_t = pt_n + 64 * 8 * 260;       // 64*256 each
    float* po_g = po_t + 64 * 256;
    float* po_a = po_g + 64 * 256;
    float* po_n = po_a + 64 * 256;
    float* code = po_n + 64 * 256;
    unsigned short* wb_t = (unsigned short*)(code + 64 * 256);  // 65536 bf16 each
    unsigned short* wb_g = wb_t + 65536;
    unsigned short* wb_d = wb_g + 65536;

    wprep_kernel<<<dim3(32, 3), 256, 0, stream>>>(Wt, Wg, Wd, wb_t, wb_g, wb_d);

    score_pool_kernel<false><<<dim3(32, 64), 256, 0, stream>>>(token_feat, token_mask, wb_t, bt, vt, ct, pt_t, 2048);
    score_pool_kernel<true ><<<dim3(8, 64),  256, 0, stream>>>(graph_feat, graph_mask, wb_g, bg, vg, cg, pt_g, 512);
    score_pool_kernel<false><<<dim3(8, 64),  256, 0, stream>>>(da_feat, da_mask, wb_d, bd, vd, cd, pt_a, 512);
    score_pool_kernel<false><<<dim3(8, 64),  256, 0, stream>>>(dn_feat, dn_mask, wb_d, bd, vd, cd, pt_n, 512);

    combine_kernel<<<dim3(64, 4), 256, 0, stream>>>(pt_t, pt_g, pt_a, pt_n, po_t, po_g, po_a, po_n);

    code_kernel<<<64, 256, 0, stream>>>(po_t, po_g, Wf, bf, code);
    loss_kernel<<<1, 256, 0, stream>>>(code, po_a, po_n, (float*)d_out);
}